// Round 17
// baseline (394.156 us; speedup 1.0000x reference)
//
#include <hip/hip_runtime.h>
#include <math.h>

#define NNODES 20000
#define NEDGES 320000
#define FDIM 64
#define NHEAD 4
#define NGR 64
#define LATD 512
#define HF 256                // NHEAD*FDIM
#define NEP (NEDGES + NNODES) // 340000
#define AGGIN 832             // FDIM*(1+3*NHEAD)
#define MPAD 20032

#define EDGE_BLOCKS4 ((NEP + 1023) / 1024)  // 333, 4 edges/thread
#define CONV_N (HF * FDIM + 2 * HF * HF)    // 147456
#define CONV_BLOCKS ((CONV_N + 255) / 256)  // 576
#define ENC_BLOCKS (NNODES / 32)            // 625
#define FW_BLOCKS (2 * 8 * 13)              // 208 (head x ctile x jtile)
#define FWB_BLOCKS 4                        // 1024 bias outputs
#define GEMM_BLOCKS (NNODES / 32)           // 625
#define SLAB_BLOCKS (NNODES / 32)           // 625
#define AGGR_BLOCKS (NNODES / 4)            // 5000

typedef float f32x4 __attribute__((ext_vector_type(4)));
typedef _Float16 f16x8 __attribute__((ext_vector_type(8)));
typedef unsigned short u16x8 __attribute__((ext_vector_type(8)));

__device__ inline unsigned short f2h(float f) {
    _Float16 h = (_Float16)f;
    unsigned short u;
    __builtin_memcpy(&u, &h, 2);
    return u;
}
__device__ inline float h2f(unsigned short u) {
    _Float16 h;
    __builtin_memcpy(&h, &u, 2);
    return (float)h;
}

// ---------------- params ----------------
struct MegaParams {
    const float *sfeat, *bfeat, *smask, *bmask;
    const int *ei, *batch;
    const float *sW, *sb, *bW, *bb;
    const float *W1, *as1, *ad1, *b1;
    const float *W2, *as2, *ad2, *b2;
    const float *W3, *as3, *ad3, *b3;
    const float *aggW, *aggb, *muW, *mub, *vW, *varb;
    float *out;
    unsigned short *h, *x0, *xA, *W1f, *W2f, *W3f;
    float *s, *d, *g, *lat, *Wf, *bf;
    int *offs, *cnt, *cnt2, *csr, *gi;
    int fused;
};

// ---------------- phase bodies ----------------

__device__ __forceinline__ void count_body(int vb, int t,
    const int* __restrict__ ei, int* __restrict__ cnt)
{
    int i0 = vb * 1024 + t;
#pragma unroll
    for (int u = 0; u < 4; u++) {
        int i = i0 + u * 256;
        if (i < NEDGES) {
            atomicAdd(&cnt[ei[NEDGES + i]], 1);
        } else if (i < NEP) {
            atomicAdd(&cnt[i - NEDGES], 1); // self loop
        }
    }
}

__device__ __forceinline__ void convert_body(int vb, int t,
    const float* __restrict__ W1, const float* __restrict__ W2, const float* __restrict__ W3,
    unsigned short* __restrict__ W1f, unsigned short* __restrict__ W2f,
    unsigned short* __restrict__ W3f)
{
    int i = vb * 256 + t;
    const int n1 = HF * FDIM, n2 = HF * HF;
    const float* src; unsigned short* dst; int j;
    if (i < n1) { src = W1; dst = W1f; j = i; }
    else if (i < n1 + n2) { src = W2; dst = W2f; j = i - n1; }
    else if (i < n1 + 2 * n2) { src = W3; dst = W3f; j = i - n1 - n2; }
    else return;
    dst[j] = f2h(src[j]);
}

// encode: x-tile staged in LDS; K chunked into two 64-wide halves so LDS =
// 25.5 KB (was 50.7) -> 6 blocks/CU. Accumulation order k4 = 0..15 then
// 16..31 == original 0..31 -> bit-identical.
__device__ __forceinline__ void encode_body(int venc, int t, float* wlds, float* xlds,
    const float* __restrict__ sfeat, const float* __restrict__ bfeat,
    const float* __restrict__ smask, const float* __restrict__ bmask,
    const float* __restrict__ sW, const float* __restrict__ sb,
    const float* __restrict__ bW, const float* __restrict__ bb,
    const int* __restrict__ batch,
    unsigned short* __restrict__ x0, int* __restrict__ g)
{
    int nb0 = venc * 32;
    int lane = t & 63, wave = t >> 6;
    int nb = nb0 + wave * 8;

    float acc[8];
#pragma unroll
    for (int i = 0; i < 8; i++) acc[i] = 0.f;

#pragma unroll
    for (int half = 0; half < 2; half++) {
        if (half) __syncthreads();   // previous half fully consumed before overwrite
        // wlds: 64 rows x 16 float4 (this K-half of sW)
#pragma unroll
        for (int it = 0; it < 4; it++) {
            int idx = it * 256 + t;          // 0..1023
            int f = idx >> 4, k4i = idx & 15;
            float4 v = *(const float4*)(sW + f * 128 + half * 64 + k4i * 4);
            *(float4*)(&wlds[f * 68 + k4i * 4]) = v;
        }
        // xlds: 32 rows x 16 float4 (this K-half of the node tile)
#pragma unroll
        for (int it = 0; it < 2; it++) {
            int idx = it * 256 + t;          // 0..511
            int node = idx >> 4, k4i = idx & 15;
            float4 v = *(const float4*)(sfeat + (size_t)(nb0 + node) * 128 + half * 64 + k4i * 4);
            *(float4*)(&xlds[node * 68 + k4i * 4]) = v;
        }
        __syncthreads();

        for (int k4 = 0; k4 < 16; k4++) {
            float4 wv = *(const float4*)(&wlds[lane * 68 + k4 * 4]);
#pragma unroll
            for (int i = 0; i < 8; i++) {
                float4 xv = *(const float4*)(&xlds[(wave * 8 + i) * 68 + k4 * 4]);
                acc[i] += xv.x * wv.x + xv.y * wv.y + xv.z * wv.z + xv.w * wv.w;
            }
        }
    }

    float bwr[5];
#pragma unroll
    for (int k = 0; k < 5; k++) bwr[k] = bW[lane * 5 + k];
    float sbv = sb[lane], bbv = bb[lane];

    int curb = batch[nb];
    float m = 0.f;
#pragma unroll
    for (int i = 0; i < 8; i++) {
        int node = nb + i;
        float accb = 0.f;
#pragma unroll
        for (int k = 0; k < 5; k++) accb += bfeat[node * 5 + k] * bwr[k];
        float sv = fmaxf(acc[i] + sbv, 0.f);
        float bv = fmaxf(accb + bbv, 0.f);
        float val = sv * smask[node] + bv * bmask[node];
        x0[(size_t)node * FDIM + lane] = f2h(val);
        int b = batch[node];
        if (b != curb) {
            atomicMax(&g[curb * AGGIN + lane], __float_as_int(m));
            m = 0.f; curb = b;
        }
        m = fmaxf(m, val);
    }
    atomicMax(&g[curb * AGGIN + lane], __float_as_int(m));
}

// fused tail weights: Wf[head][c][j] = sum_k M[c,k]*aggW[k,j]  (M = muW or vW)
// round-17 FIX of round-16 bug: K-chunk 32 shrinks only the K-extent.
//   As = [64 c-rows][32 k + pad]  (stride 36)
//   Bs = [32 k-rows][64 j + pad]  (stride 68)  <- j-extent must stay 64!
// (round-16 wrongly used stride 36 for Bs -> rows overlapped, half the
//  j-range never loaded, + OOB aggW reads at kt=15.)
// Same kt*32+kk accumulation order as the verified 8x64 version -> bit-identical.
__device__ __forceinline__ void fw_body(int vb, int t, float* lds,
    const float* __restrict__ muW, const float* __restrict__ vW,
    const float* __restrict__ aggW, float* __restrict__ Wf)
{
    float* As = lds;               // [64][36]
    float* Bs = lds + 64 * 36;     // [32][68]
    int head = vb / 104, rem = vb % 104;
    int ct = rem / 13, jt = rem % 13;
    int c0 = ct * 64, j0 = jt * 64;
    const float* M = head ? vW : muW;
    int ty = t >> 4, tx = t & 15;

    float acc[4][4];
#pragma unroll
    for (int a = 0; a < 4; a++)
#pragma unroll
        for (int b = 0; b < 4; b++) acc[a][b] = 0.f;

    for (int kt = 0; kt < 16; kt++) {
        int k0 = kt * 32;
#pragma unroll
        for (int it = 0; it < 2; it++) {
            int idx = it * 256 + t;          // 0..511
            // As: 64 rows x 8 float4 (32 k-values per c-row)
            int arow = idx >> 3, ac4 = (idx & 7) * 4;
            *(float4*)&As[arow * 36 + ac4] =
                *(const float4*)&M[(size_t)(c0 + arow) * 512 + k0 + ac4];
            // Bs: 32 rows x 16 float4 (full 64 j-values per k-row)
            int brow = idx >> 4, bc4 = (idx & 15) * 4;
            *(float4*)&Bs[brow * 68 + bc4] =
                *(const float4*)&aggW[(size_t)(k0 + brow) * 832 + j0 + bc4];
        }
        __syncthreads();
#pragma unroll 4
        for (int kk = 0; kk < 32; kk++) {
            float a0 = As[(ty * 4 + 0) * 36 + kk];
            float a1 = As[(ty * 4 + 1) * 36 + kk];
            float a2 = As[(ty * 4 + 2) * 36 + kk];
            float a3 = As[(ty * 4 + 3) * 36 + kk];
            float4 b4 = *(const float4*)&Bs[kk * 68 + tx * 4];
            acc[0][0] += a0 * b4.x; acc[0][1] += a0 * b4.y; acc[0][2] += a0 * b4.z; acc[0][3] += a0 * b4.w;
            acc[1][0] += a1 * b4.x; acc[1][1] += a1 * b4.y; acc[1][2] += a1 * b4.z; acc[1][3] += a1 * b4.w;
            acc[2][0] += a2 * b4.x; acc[2][1] += a2 * b4.y; acc[2][2] += a2 * b4.z; acc[2][3] += a2 * b4.w;
            acc[3][0] += a3 * b4.x; acc[3][1] += a3 * b4.y; acc[3][2] += a3 * b4.z; acc[3][3] += a3 * b4.w;
        }
        __syncthreads();
    }
#pragma unroll
    for (int a = 0; a < 4; a++) {
        float4 v; v.x = acc[a][0]; v.y = acc[a][1]; v.z = acc[a][2]; v.w = acc[a][3];
        *(float4*)&Wf[((size_t)(head * 512) + c0 + ty * 4 + a) * 832 + j0 + tx * 4] = v;
    }
}

// fused tail bias: bf[head][c] = dot(M[c,:], aggb) + base[c]
__device__ __forceinline__ void fwbias_body(int vb, int t,
    const float* __restrict__ muW, const float* __restrict__ mub,
    const float* __restrict__ vW, const float* __restrict__ varb,
    const float* __restrict__ aggb, float* __restrict__ bf)
{
    int idx = vb * 256 + t;          // 0..1023
    int head = idx >> 9, c = idx & 511;
    const float* M = head ? vW : muW;
    const float* base = head ? varb : mub;
    const float4* mv = (const float4*)(M + (size_t)c * 512);
    const float4* av = (const float4*)aggb;
    float acc = 0.f;
#pragma unroll 4
    for (int k = 0; k < 512 / 4; k++) {
        float4 a = mv[k], b = av[k];
        acc += a.x * b.x + a.y * b.y + a.z * b.z + a.w * b.w;
    }
    bf[idx] = acc + base[c];
}

__device__ __forceinline__ void scatter_body(int vb, int t,
    const int* __restrict__ ei, const int* __restrict__ offs,
    int* __restrict__ cnt2, int* __restrict__ csr_src)
{
    int i0 = vb * 1024 + t;
    int sv[4], dv[4];
#pragma unroll
    for (int u = 0; u < 4; u++) {
        int i = i0 + u * 256;
        if (i < NEDGES) { sv[u] = ei[i]; dv[u] = ei[NEDGES + i]; }
        else if (i < NEP) { sv[u] = i - NEDGES; dv[u] = i - NEDGES; }
        else { sv[u] = -1; dv[u] = 0; }
    }
#pragma unroll
    for (int u = 0; u < 4; u++) {
        if (sv[u] >= 0) {
            int p = offs[dv[u]] + atomicAdd(&cnt2[dv[u]], 1);
            csr_src[p] = sv[u];
        }
    }
}

// 32 nodes/block, 2x4 acc — round-13 configuration (B-read amortization wins)
template <int K>
__device__ __forceinline__ void gemm_body(int vbg, int t,
    const unsigned short* __restrict__ xf, const unsigned short* __restrict__ Wf,
    const float* __restrict__ a_src, const float* __restrict__ a_dst,
    unsigned short* __restrict__ h, float* __restrict__ s, float* __restrict__ d)
{
    constexpr int NCHUNK = K / 64;
    int lane = t & 63, w = t >> 6;
    int colid = lane & 15, quad = lane >> 4;
    int nb = vbg * 32;

    f32x4 acc[2][4];
#pragma unroll
    for (int mt = 0; mt < 2; mt++)
#pragma unroll
        for (int nt = 0; nt < 4; nt++)
#pragma unroll
            for (int r = 0; r < 4; r++) acc[mt][nt][r] = 0.f;

#pragma unroll
    for (int c = 0; c < NCHUNK; c++) {
        const int kc = c * 64;
        f16x8 ah[2][2], bh[4][2];
#pragma unroll
        for (int half = 0; half < 2; half++) {
#pragma unroll
            for (int mt = 0; mt < 2; mt++) {
                size_t aoff = (size_t)(nb + mt * 16 + colid) * K + kc + half * 32 + quad * 8;
                ah[mt][half] = *(const f16x8*)&xf[aoff];
            }
#pragma unroll
            for (int nt = 0; nt < 4; nt++) {
                size_t boff = (size_t)(w * 64 + nt * 16 + colid) * K + kc + half * 32 + quad * 8;
                bh[nt][half] = *(const f16x8*)&Wf[boff];
            }
        }
        __builtin_amdgcn_sched_barrier(0);
#pragma unroll
        for (int half = 0; half < 2; half++)
#pragma unroll
            for (int mt = 0; mt < 2; mt++)
#pragma unroll
                for (int nt = 0; nt < 4; nt++)
                    acc[mt][nt] = __builtin_amdgcn_mfma_f32_16x16x32_f16(ah[mt][half], bh[nt][half], acc[mt][nt], 0, 0, 0);
    }

    // write h (fp16): C/D layout row=quad*4+r (node), col=colid
#pragma unroll
    for (int mt = 0; mt < 2; mt++) {
#pragma unroll
        for (int r = 0; r < 4; r++) {
            int node = nb + mt * 16 + quad * 4 + r;
#pragma unroll
            for (int nt = 0; nt < 4; nt++)
                h[(size_t)node * HF + w * 64 + nt * 16 + colid] = f2h(acc[mt][nt][r]);
        }
    }

    // attention projections for head w
    float as_r[4], ad_r[4];
#pragma unroll
    for (int nt = 0; nt < 4; nt++) {
        as_r[nt] = a_src[w * 64 + nt * 16 + colid];
        ad_r[nt] = a_dst[w * 64 + nt * 16 + colid];
    }
#pragma unroll
    for (int mt = 0; mt < 2; mt++) {
#pragma unroll
        for (int r = 0; r < 4; r++) {
            float ps = 0.f, pd = 0.f;
#pragma unroll
            for (int nt = 0; nt < 4; nt++) {
                ps += acc[mt][nt][r] * as_r[nt];
                pd += acc[mt][nt][r] * ad_r[nt];
            }
#pragma unroll
            for (int m = 1; m < 16; m <<= 1) {
                ps += __shfl_xor(ps, m, 64);
                pd += __shfl_xor(pd, m, 64);
            }
            if (colid == 0) {
                int node = nb + mt * 16 + quad * 4 + r;
                s[(size_t)node * NHEAD + w] = ps;
                d[(size_t)node * NHEAD + w] = pd;
            }
        }
    }
}

// GAT softmax + aggregate, one wave per node.
// Round-13: chunk-0 h-gathers issued BEFORE the softmax reduction.
__device__ __forceinline__ void aggr_body(int vba, int t,
    const unsigned short* __restrict__ h, const float* __restrict__ s, const float* __restrict__ d,
    const int* __restrict__ offs, const int* __restrict__ csr_src,
    const float* __restrict__ bias, unsigned short* __restrict__ out)
{
    int lane = t & 63;
    int wv = t >> 6;
    int node = vba * 4 + wv;
    int eh = lane >> 5;
    int p = lane & 31;
    int hd2 = p >> 3;
    int f0 = p * 8;
    int lo = offs[node], hi = offs[node + 1];
    int deg = hi - lo;

    float a[8];
#pragma unroll
    for (int j = 0; j < 8; j++) a[j] = 0.f;
    float inv;

    if (deg <= 64) {
        int slot = lane >> 2, hd = lane & 3;
        float dn = d[(size_t)node * NHEAD + hd];
        float ev[4];
        int sv[4];
#pragma unroll
        for (int c = 0; c < 4; c++) {
            int k = c * 16 + slot;
            float e = -3.402823466e38f;
            int src = 0;
            if (k < deg) {
                src = csr_src[lo + k];
                float ee = s[(size_t)src * NHEAD + hd] + dn;
                e = fmaxf(ee, 0.2f * ee);
            }
            ev[c] = e; sv[c] = src;
        }

        // early: shuffle chunk-0 source rows and ISSUE the gathers now
        int sr0[16];
        u16x8 hv0[16];
#pragma unroll
        for (int cc = 0; cc < 2; cc++)
#pragma unroll
            for (int u = 0; u < 8; u++) {
                int sl = (u * 2 + eh) * 4 + hd2;
                sr0[cc * 8 + u] = __shfl(sv[cc], sl);
            }
#pragma unroll
        for (int u = 0; u < 16; u++)
            hv0[u] = *(const u16x8*)(h + (size_t)sr0[u] * HF + f0);

        // softmax while the gathers are in flight
        float mx = fmaxf(fmaxf(ev[0], ev[1]), fmaxf(ev[2], ev[3]));
#pragma unroll
        for (int m = 4; m < 64; m <<= 1) mx = fmaxf(mx, __shfl_xor(mx, m, 64));
        float den = 0.f;
#pragma unroll
        for (int c = 0; c < 4; c++) {
            ev[c] = __expf(ev[c] - mx);  // invalid slots -> 0
            den += ev[c];
        }
#pragma unroll
        for (int m = 4; m < 64; m <<= 1) den += __shfl_xor(den, m, 64);

        inv = 1.f / __shfl(den, hd2);

        // chunk-0 FMA (ex shuffles post-exp; same order as before)
#pragma unroll
        for (int cc = 0; cc < 2; cc++)
#pragma unroll
            for (int u = 0; u < 8; u++) {
                int sl = (u * 2 + eh) * 4 + hd2;
                float ex = __shfl(ev[cc], sl);
                int uu = cc * 8 + u;
#pragma unroll
                for (int j = 0; j < 8; j++) a[j] += ex * h2f(hv0[uu][j]);
            }

        // chunk 1 (edges 32..63) — rare (deg > 32), serial as before
        if (deg > 32) {
            float ex[16]; int sr[16]; u16x8 hv[16];
#pragma unroll
            for (int cc = 0; cc < 2; cc++) {
                int c = 2 + cc;
#pragma unroll
                for (int u = 0; u < 8; u++) {
                    int sl = (u * 2 + eh) * 4 + hd2;
                    ex[cc * 8 + u] = __shfl(ev[c], sl);
                    sr[cc * 8 + u] = __shfl(sv[c], sl);
                }
            }
#pragma unroll
            for (int u = 0; u < 16; u++)
                hv[u] = *(const u16x8*)(h + (size_t)sr[u] * HF + f0);
#pragma unroll
            for (int u = 0; u < 16; u++)
#pragma unroll
                for (int j = 0; j < 8; j++) a[j] += ex[u] * h2f(hv[u][j]);
        }
    } else {
        float dn2 = d[(size_t)node * NHEAD + hd2];
        float mx = -3.402823466e38f;
        for (int i = lo; i < hi; i++) {
            int src = csr_src[i];
            float e = s[(size_t)src * NHEAD + hd2] + dn2;
            e = fmaxf(e, 0.2f * e);
            mx = fmaxf(mx, e);
        }
        float den = 0.f;
        for (int i = lo + eh; i < hi; i += 2) {
            int src = csr_src[i];
            float e = s[(size_t)src * NHEAD + hd2] + dn2;
            e = fmaxf(e, 0.2f * e);
            float ex = __expf(e - mx);
            den += ex;
            u16x8 hv = *(const u16x8*)(h + (size_t)src * HF + f0);
#pragma unroll
            for (int j = 0; j < 8; j++) a[j] += ex * h2f(hv[j]);
        }
        den += __shfl_xor(den, 32, 64);
        inv = 1.f / den;
    }

#pragma unroll
    for (int j = 0; j < 8; j++) a[j] += __shfl_xor(a[j], 32, 64);

    if (eh == 0) {
        u16x8 ov;
#pragma unroll
        for (int j = 0; j < 8; j++)
            ov[j] = f2h(fmaxf(a[j] * inv + bias[f0 + j], 0.f));
        *(u16x8*)(out + (size_t)node * HF + f0) = ov;
    }
}

// per-graph column max via register running-max; ~1 atomic flush / 32 rows
__device__ __forceinline__ void slab_body(int vbs, int t,
    const unsigned short* __restrict__ x, const int* __restrict__ batch,
    int* __restrict__ g, int coloff)
{
    int f = t;
    int r0 = vbs * 32;
    int cur = batch[r0];
    float m = 0.f;
    for (int r = r0; r < r0 + 32; r += 4) {
        float v[4]; int bb[4];
#pragma unroll
        for (int i = 0; i < 4; i++) {
            v[i] = h2f(x[(size_t)(r + i) * HF + f]);
            bb[i] = batch[r + i];
        }
#pragma unroll
        for (int i = 0; i < 4; i++) {
            if (bb[i] != cur) {
                atomicMax(&g[cur * AGGIN + coloff + f], __float_as_int(m));
                m = 0.f; cur = bb[i];
            }
            m = fmaxf(m, v[i]);
        }
    }
    atomicMax(&g[cur * AGGIN + coloff + f], __float_as_int(m));
}

// ---------------- kernels ----------------

// dispatch 1: fw FIRST (longest blocks -> earliest issue), then count/convert/encode
// LDS 25.5 KB (was 50.7) -> 6 blocks/CU
__global__ __launch_bounds__(256) void k_prep_enc(MegaParams P)
{
    __shared__ float smemf[64 * 68 + 32 * 68];   // 26112 B; fw uses 17920 B of it
    int b = blockIdx.x;
    int fwtot = P.fused ? (FW_BLOCKS + FWB_BLOCKS) : 0;
    if (b < fwtot) {
        if (b < FW_BLOCKS)
            fw_body(b, threadIdx.x, smemf, P.muW, P.vW, P.aggW, P.Wf);
        else
            fwbias_body(b - FW_BLOCKS, threadIdx.x, P.muW, P.mub, P.vW, P.varb,
                        P.aggb, P.bf);
        return;
    }
    b -= fwtot;
    if (b < EDGE_BLOCKS4) {
        count_body(b, threadIdx.x, P.ei, P.cnt);
    } else if (b < EDGE_BLOCKS4 + CONV_BLOCKS) {
        convert_body(b - EDGE_BLOCKS4, threadIdx.x, P.W1, P.W2, P.W3,
                     P.W1f, P.W2f, P.W3f);
    } else {
        float* wlds = smemf;
        float* xlds = smemf + 64 * 68;
        encode_body(b - (EDGE_BLOCKS4 + CONV_BLOCKS), threadIdx.x, wlds, xlds,
                    P.sfeat, P.bfeat, P.smask, P.bmask, P.sW, P.sb, P.bW, P.bb,
                    P.batch, P.x0, P.gi);
    }
}

// CSR scan: 1024 threads — verbatim baseline
__global__ __launch_bounds__(1024) void k_scan(MegaParams P)
{
    const int* deg = P.cnt;
    int* offs = P.offs;
    __shared__ int wt[16];
    const int per = (NNODES + 1023) / 1024; // 20
    int t = threadIdx.x, lane = t & 63, w = t >> 6;
    int start = t * per;
    int end = start + per; if (end > NNODES) end = NNODES;
    int s = 0;
    for (int i = start; i < end; i++) s += deg[i];
    int pref = s;
#pragma unroll
    for (int m = 1; m < 64; m <<= 1) {
        int v = __shfl_up(pref, m, 64);
        if (lane >= m) pref += v;
    }
    if (lane == 63) wt[w] = pref;
    __syncthreads();
    int wadd = 0;
    for (int i = 0; i < w; i++) wadd += wt[i];
    int acc = wadd + pref - s; // exclusive prefix
    for (int i = start; i < end; i++) { offs[i] = acc; acc += deg[i]; }
    if (t == 1023) offs[NNODES] = NEP;
}

// GEMM with extra blocks doing either scatter (slabcol<0) or seg-max slab
template <int K>
__global__ __launch_bounds__(256, 2) void k_gemm(MegaParams P,
    const unsigned short* xf, const unsigned short* Wf,
    const float* a_src, const float* a_dst, int slabcol)
{
    if ((int)blockIdx.x >= GEMM_BLOCKS) {
        if (slabcol >= 0)
            slab_body(blockIdx.x - GEMM_BLOCKS, threadIdx.x, xf, P.batch, P.gi, slabcol);
        else
            scatter_body(blockIdx.x - GEMM_BLOCKS, threadIdx.x, P.ei, P.offs, P.cnt2, P.csr);
        return;
    }
    gemm_body<K>(blockIdx.x, threadIdx.x, xf, Wf, a_src, a_dst, P.h, P.s, P.d);
}

__global__ __launch_bounds__(256) void k_aggr(MegaParams P, const float* bias)
{
    aggr_body(blockIdx.x, threadIdx.x, P.h, P.s, P.d, P.offs, P.csr, bias, P.xA);
}

__global__ __launch_bounds__(256) void k_slab(MegaParams P, int coloff)
{
    slab_body(blockIdx.x, threadIdx.x, P.xA, P.batch, P.gi, coloff);
}

// fused tail: out[half,r,c] = g[r,:] . Wf[half,c,:] + bf[half,c]
__global__ __launch_bounds__(256) void k_head_fused(MegaParams P)
{
    int idx = blockIdx.x * 256 + threadIdx.x; // 2*64*512
    int half = idx >> 15;
    int j = idx & 32767;
    int r = j >> 9, c = j & 511;
    const float4* gv = (const float4*)(P.g + (size_t)r * AGGIN);
    const float4* wv = (const float4*)(P.Wf + ((size_t)(half * 512) + c) * 832);
    float acc = 0.f;
#pragma unroll 4
    for (int k = 0; k < AGGIN / 4; k++) {
        float4 a = gv[k], w = wv[k];
        acc += a.x * w.x + a.y * w.y + a.z * w.z + a.w * w.w;
    }
    P.out[idx] = acc + P.bf[half * 512 + c];
}

// fallback tail (verbatim baseline)
__global__ __launch_bounds__(256) void k_latent(MegaParams P)
{
    int idx = blockIdx.x * 256 + threadIdx.x; // 64*512
    int r = idx >> 9, c = idx & 511;
    const float4* gv = (const float4*)(P.g + (size_t)r * AGGIN);
    const float4* wv = (const float4*)(P.aggW + (size_t)c * AGGIN);
    float acc = 0.f;
#pragma unroll 4
    for (int k = 0; k < AGGIN / 4; k++) {
        float4 a = gv[k], w = wv[k];
        acc += a.x * w.x + a.y * w.y + a.z * w.z + a.w * w.w;
    }
    P.lat[idx] = acc + P.aggb[c];
}

__global__ __launch_bounds__(256) void k_head(MegaParams P)
{
    int idx = blockIdx.x * 256 + threadIdx.x; // 2*64*512
    int half = idx >> 15;
    int j = idx & 32767;
    int r = j >> 9, c = j & 511;
    const float* W = half ? P.vW : P.muW;
    const float* bb = half ? P.varb : P.mub;
    const float4* lv = (const float4*)(P.lat + (size_t)r * LATD);
    const float4* wv = (const float4*)(W + (size_t)c * LATD);
    float acc = 0.f;
#pragma unroll 4
    for (int k = 0; k < LATD / 4; k++) {
        float4 a = lv[k], w = wv[k];
        acc += a.x * w.x + a.y * w.y + a.z * w.z + a.w * w.w;
    }
    P.out[idx] = acc + bb[c];
}

// ---------------- launch ----------------
static inline size_t align16(size_t x) { return (x + 15) & ~(size_t)15; }

extern "C" void kernel_launch(void* const* d_in, const int* in_sizes, int n_in,
                              void* d_out, int out_size, void* d_ws, size_t ws_size,
                              hipStream_t stream)
{
    MegaParams P;
    P.sfeat = (const float*)d_in[0];
    P.bfeat = (const float*)d_in[1];
    P.smask = (const float*)d_in[2];
    P.bmask = (const float*)d_in[3];
    P.ei    = (const int*)d_in[4];
    P.batch = (const int*)d_in[5];
    P.sW = (const float*)d_in[6];
    P.sb = (const float*)d_in[7];
    P.bW = (const float*)d_in[8];
    P.bb = (const float*)d_in[9];
    P.W1 = (const float*)d_in[10];
    P.as1 = (const float*)d_in[11];
    P.ad1 = (const float*)d_in[12];
    P.b1 = (const float*)d_in[13];
    P.W2 = (const float*)d_in[14];
    P.as2 = (const float*)d_in[15];
    P.ad2 = (const float*)d_in[16];
    P.b2 = (const float*)d_in[17];
    P.W3 = (const float*)d_in[18];
    P.as3 = (const float*)d_in[19];
    P.ad3 = (const float*)d_in[20];
    P.b3 = (const float*)d_in[21];
    P.aggW = (const float*)d_in[22];
    P.aggb = (const float*)d_in[23];
    P.muW = (const float*)d_in[24];
    P.mub = (const float*)d_in[25];
    P.vW = (const float*)d_in[26];
    P.varb = (const float*)d_in[27];
    P.out = (float*)d_out;

    char* ws = (char*)d_ws;
    size_t off = 0;
    P.h  = (unsigned short*)(ws + off); off = align16(off + (size_t)NNODES * HF * 2);
    P.x0 = (unsigned short*)(ws + off); off = align16(off + (size_t)MPAD * FDIM * 2);
    P.xA = (unsigned short*)(ws + off); off = align16(off + (size_t)MPAD * HF * 2);
    P.s  = (float*)(ws + off); off = align16(off + (size_t)NNODES * NHEAD * 4);
    P.d  = (float*)(ws + off); off = align16(off + (size_t)NNODES * NHEAD * 4);
    P.offs = (int*)(ws + off); off = align16(off + (size_t)(NNODES + 1) * 4);
    // zero-init region: cnt | cnt2 | g (single memset)
    size_t zstart = off;
    P.cnt  = (int*)(ws + off); off = align16(off + (size_t)NNODES * 4);
    P.cnt2 = (int*)(ws + off); off = align16(off + (size_t)NNODES * 4);
    P.g    = (float*)(ws + off); off = align16(off + (size_t)NGR * AGGIN * 4);
    size_t zbytes = off - zstart;
    P.csr = (int*)(ws + off); off = align16(off + (size_t)NEP * 4);
    P.lat = (float*)(ws + off); off = align16(off + (size_t)NGR * LATD * 4);
    P.W1f = (unsigned short*)(ws + off); off = align16(off + (size_t)HF * FDIM * 2);
    P.W2f = (unsigned short*)(ws + off); off = align16(off + (size_t)HF * HF * 2);
    P.W3f = (unsigned short*)(ws + off); off = align16(off + (size_t)HF * HF * 2);
    // fused tail buffers (optional — runtime ws_size check)
    P.Wf = (float*)(ws + off); off = align16(off + (size_t)2 * 512 * 832 * 4);
    P.bf = (float*)(ws + off); off = align16(off + (size_t)2 * 512 * 4);
    P.fused = (off <= ws_size) ? 1 : 0;

    P.gi = (int*)P.g;

    hipMemsetAsync(ws + zstart, 0, zbytes, stream);

    // 10 dispatches (fused) / 11 (fallback)
    int prep_blocks = EDGE_BLOCKS4 + CONV_BLOCKS + ENC_BLOCKS
                    + (P.fused ? (FW_BLOCKS + FWB_BLOCKS) : 0);
    k_prep_enc<<<prep_blocks, 256, 0, stream>>>(P);
    k_scan<<<1, 1024, 0, stream>>>(P);

    // gemm1 + scatter ride together (mutually independent; both complete before aggr1)
    k_gemm<FDIM><<<GEMM_BLOCKS + EDGE_BLOCKS4, 256, 0, stream>>>(P, P.x0, P.W1f, P.as1, P.ad1, -1);
    k_aggr<<<AGGR_BLOCKS, 256, 0, stream>>>(P, P.b1);

    k_gemm<HF><<<GEMM_BLOCKS + SLAB_BLOCKS, 256, 0, stream>>>(P, P.xA, P.W2f, P.as2, P.ad2, FDIM);
    k_aggr<<<AGGR_BLOCKS, 256, 0, stream>>>(P, P.b2);

    k_gemm<HF><<<GEMM_BLOCKS + SLAB_BLOCKS, 256, 0, stream>>>(P, P.xA, P.W3f, P.as3, P.ad3, FDIM + HF);
    k_aggr<<<AGGR_BLOCKS, 256, 0, stream>>>(P, P.b3);

    k_slab<<<SLAB_BLOCKS, 256, 0, stream>>>(P, FDIM + 2 * HF);

    if (P.fused) {
        k_head_fused<<<(2 * NGR * LATD) / 256, 256, 0, stream>>>(P);
    } else {
        k_latent<<<(NGR * LATD) / 256, 256, 0, stream>>>(P);
        k_head<<<(2 * NGR * LATD) / 256, 256, 0, stream>>>(P);
    }
}

// Round 18
// 347.256 us; speedup vs baseline: 1.1351x; 1.1351x over previous
//
#include <hip/hip_runtime.h>
#include <math.h>

#define NNODES 20000
#define NEDGES 320000
#define FDIM 64
#define NHEAD 4
#define NGR 64
#define LATD 512
#define HF 256                // NHEAD*FDIM
#define NEP (NEDGES + NNODES) // 340000
#define AGGIN 832             // FDIM*(1+3*NHEAD)
#define MPAD 20032

#define EDGE_BLOCKS4 ((NEP + 1023) / 1024)  // 333, 4 edges/thread
#define CONV_N (HF * FDIM + 2 * HF * HF)    // 147456
#define CONV_BLOCKS ((CONV_N + 255) / 256)  // 576
#define ENC_BLOCKS (NNODES / 32)            // 625
#define FW_BLOCKS (2 * 8 * 13)              // 208 (head x ctile x jtile)
#define FWB_BLOCKS 4                        // 1024 bias outputs
#define GEMM_BLOCKS (NNODES / 32)           // 625
#define SLAB_BLOCKS (NNODES / 32)           // 625
#define AGGR_BLOCKS (NNODES / 4)            // 5000

typedef float f32x4 __attribute__((ext_vector_type(4)));
typedef _Float16 f16x8 __attribute__((ext_vector_type(8)));
typedef unsigned short u16x8 __attribute__((ext_vector_type(8)));

__device__ inline unsigned short f2h(float f) {
    _Float16 h = (_Float16)f;
    unsigned short u;
    __builtin_memcpy(&u, &h, 2);
    return u;
}
__device__ inline float h2f(unsigned short u) {
    _Float16 h;
    __builtin_memcpy(&h, &u, 2);
    return (float)h;
}

// ---------------- params ----------------
struct MegaParams {
    const float *sfeat, *bfeat, *smask, *bmask;
    const int *ei, *batch;
    const float *sW, *sb, *bW, *bb;
    const float *W1, *as1, *ad1, *b1;
    const float *W2, *as2, *ad2, *b2;
    const float *W3, *as3, *ad3, *b3;
    const float *aggW, *aggb, *muW, *mub, *vW, *varb;
    float *out;
    unsigned short *h, *x0, *xA, *W1f, *W2f, *W3f;
    float *s, *d, *g, *lat, *Wf, *bf;
    int *offs, *cnt, *cnt2, *csr, *gi;
    int fused;
};

// ---------------- phase bodies ----------------

__device__ __forceinline__ void count_body(int vb, int t,
    const int* __restrict__ ei, int* __restrict__ cnt)
{
    int i0 = vb * 1024 + t;
#pragma unroll
    for (int u = 0; u < 4; u++) {
        int i = i0 + u * 256;
        if (i < NEDGES) {
            atomicAdd(&cnt[ei[NEDGES + i]], 1);
        } else if (i < NEP) {
            atomicAdd(&cnt[i - NEDGES], 1); // self loop
        }
    }
}

__device__ __forceinline__ void convert_body(int vb, int t,
    const float* __restrict__ W1, const float* __restrict__ W2, const float* __restrict__ W3,
    unsigned short* __restrict__ W1f, unsigned short* __restrict__ W2f,
    unsigned short* __restrict__ W3f)
{
    int i = vb * 256 + t;
    const int n1 = HF * FDIM, n2 = HF * HF;
    const float* src; unsigned short* dst; int j;
    if (i < n1) { src = W1; dst = W1f; j = i; }
    else if (i < n1 + n2) { src = W2; dst = W2f; j = i - n1; }
    else if (i < n1 + 2 * n2) { src = W3; dst = W3f; j = i - n1 - n2; }
    else return;
    dst[j] = f2h(src[j]);
}

// encode: x-tile staged in LDS (round-9 verified: fixed wave-uniform s_load serialization)
__device__ __forceinline__ void encode_body(int venc, int t, float* wlds, float* xlds,
    const float* __restrict__ sfeat, const float* __restrict__ bfeat,
    const float* __restrict__ smask, const float* __restrict__ bmask,
    const float* __restrict__ sW, const float* __restrict__ sb,
    const float* __restrict__ bW, const float* __restrict__ bb,
    const int* __restrict__ batch,
    unsigned short* __restrict__ x0, int* __restrict__ g)
{
#pragma unroll
    for (int it = 0; it < 8; it++) {
        int idx = it * 256 + t;
        int f = idx >> 5, k4 = idx & 31;
        float4 v = *(const float4*)(sW + f * 128 + k4 * 4);
        *(float4*)(&wlds[f * 132 + k4 * 4]) = v;
    }
    int nb0 = venc * 32;
#pragma unroll
    for (int it = 0; it < 4; it++) {
        int idx = it * 256 + t;          // 0..1023
        int node = idx >> 5, k4 = idx & 31;
        float4 v = *(const float4*)(sfeat + (size_t)(nb0 + node) * 128 + k4 * 4);
        *(float4*)(&xlds[node * 132 + k4 * 4]) = v;
    }
    __syncthreads();

    int lane = t & 63, wave = t >> 6;
    int nb = nb0 + wave * 8;

    float acc[8];
#pragma unroll
    for (int i = 0; i < 8; i++) acc[i] = 0.f;

    for (int k4 = 0; k4 < 32; k4++) {
        float4 wv = *(const float4*)(&wlds[lane * 132 + k4 * 4]);
#pragma unroll
        for (int i = 0; i < 8; i++) {
            float4 xv = *(const float4*)(&xlds[(wave * 8 + i) * 132 + k4 * 4]);
            acc[i] += xv.x * wv.x + xv.y * wv.y + xv.z * wv.z + xv.w * wv.w;
        }
    }

    float bwr[5];
#pragma unroll
    for (int k = 0; k < 5; k++) bwr[k] = bW[lane * 5 + k];
    float sbv = sb[lane], bbv = bb[lane];

    int curb = batch[nb];
    float m = 0.f;
#pragma unroll
    for (int i = 0; i < 8; i++) {
        int node = nb + i;
        float accb = 0.f;
#pragma unroll
        for (int k = 0; k < 5; k++) accb += bfeat[node * 5 + k] * bwr[k];
        float sv = fmaxf(acc[i] + sbv, 0.f);
        float bv = fmaxf(accb + bbv, 0.f);
        float val = sv * smask[node] + bv * bmask[node];
        x0[(size_t)node * FDIM + lane] = f2h(val);
        int b = batch[node];
        if (b != curb) {
            atomicMax(&g[curb * AGGIN + lane], __float_as_int(m));
            m = 0.f; curb = b;
        }
        m = fmaxf(m, val);
    }
    atomicMax(&g[curb * AGGIN + lane], __float_as_int(m));
}

// fused tail weights: Wf[head][c][j] = sum_k M[c,k]*aggW[k,j]  (M = muW or vW)
// input-only; issued FIRST in dispatch 1 (round-10/11 lesson: longest block
// class must get the lowest block indices or it extends the dispatch end).
__device__ __forceinline__ void fw_body(int vb, int t, float* lds,
    const float* __restrict__ muW, const float* __restrict__ vW,
    const float* __restrict__ aggW, float* __restrict__ Wf)
{
    float* As = lds;               // [64][68]
    float* Bs = lds + 64 * 68;     // [64][68]
    int head = vb / 104, rem = vb % 104;
    int ct = rem / 13, jt = rem % 13;
    int c0 = ct * 64, j0 = jt * 64;
    const float* M = head ? vW : muW;
    int ty = t >> 4, tx = t & 15;

    float acc[4][4];
#pragma unroll
    for (int a = 0; a < 4; a++)
#pragma unroll
        for (int b = 0; b < 4; b++) acc[a][b] = 0.f;

    for (int kt = 0; kt < 8; kt++) {
        int k0 = kt * 64;
#pragma unroll
        for (int it = 0; it < 4; it++) {
            int idx = it * 256 + t;       // 0..1023 = 64 rows x 16 float4
            int row = idx >> 4, c4 = (idx & 15) * 4;
            *(float4*)&As[row * 68 + c4] = *(const float4*)&M[(size_t)(c0 + row) * 512 + k0 + c4];
            *(float4*)&Bs[row * 68 + c4] = *(const float4*)&aggW[(size_t)(k0 + row) * 832 + j0 + c4];
        }
        __syncthreads();
#pragma unroll 4
        for (int kk = 0; kk < 64; kk++) {
            float a0 = As[(ty * 4 + 0) * 68 + kk];
            float a1 = As[(ty * 4 + 1) * 68 + kk];
            float a2 = As[(ty * 4 + 2) * 68 + kk];
            float a3 = As[(ty * 4 + 3) * 68 + kk];
            float4 b4 = *(const float4*)&Bs[kk * 68 + tx * 4];
            acc[0][0] += a0 * b4.x; acc[0][1] += a0 * b4.y; acc[0][2] += a0 * b4.z; acc[0][3] += a0 * b4.w;
            acc[1][0] += a1 * b4.x; acc[1][1] += a1 * b4.y; acc[1][2] += a1 * b4.z; acc[1][3] += a1 * b4.w;
            acc[2][0] += a2 * b4.x; acc[2][1] += a2 * b4.y; acc[2][2] += a2 * b4.z; acc[2][3] += a2 * b4.w;
            acc[3][0] += a3 * b4.x; acc[3][1] += a3 * b4.y; acc[3][2] += a3 * b4.z; acc[3][3] += a3 * b4.w;
        }
        __syncthreads();
    }
#pragma unroll
    for (int a = 0; a < 4; a++) {
        float4 v; v.x = acc[a][0]; v.y = acc[a][1]; v.z = acc[a][2]; v.w = acc[a][3];
        *(float4*)&Wf[((size_t)(head * 512) + c0 + ty * 4 + a) * 832 + j0 + tx * 4] = v;
    }
}

// fused tail bias: bf[head][c] = dot(M[c,:], aggb) + base[c]
__device__ __forceinline__ void fwbias_body(int vb, int t,
    const float* __restrict__ muW, const float* __restrict__ mub,
    const float* __restrict__ vW, const float* __restrict__ varb,
    const float* __restrict__ aggb, float* __restrict__ bf)
{
    int idx = vb * 256 + t;          // 0..1023
    int head = idx >> 9, c = idx & 511;
    const float* M = head ? vW : muW;
    const float* base = head ? varb : mub;
    const float4* mv = (const float4*)(M + (size_t)c * 512);
    const float4* av = (const float4*)aggb;
    float acc = 0.f;
#pragma unroll 4
    for (int k = 0; k < 512 / 4; k++) {
        float4 a = mv[k], b = av[k];
        acc += a.x * b.x + a.y * b.y + a.z * b.z + a.w * b.w;
    }
    bf[idx] = acc + base[c];
}

__device__ __forceinline__ void scatter_body(int vb, int t,
    const int* __restrict__ ei, const int* __restrict__ offs,
    int* __restrict__ cnt2, int* __restrict__ csr_src)
{
    int i0 = vb * 1024 + t;
    int sv[4], dv[4];
#pragma unroll
    for (int u = 0; u < 4; u++) {
        int i = i0 + u * 256;
        if (i < NEDGES) { sv[u] = ei[i]; dv[u] = ei[NEDGES + i]; }
        else if (i < NEP) { sv[u] = i - NEDGES; dv[u] = i - NEDGES; }
        else { sv[u] = -1; dv[u] = 0; }
    }
#pragma unroll
    for (int u = 0; u < 4; u++) {
        if (sv[u] >= 0) {
            int p = offs[dv[u]] + atomicAdd(&cnt2[dv[u]], 1);
            csr_src[p] = sv[u];
        }
    }
}

// 32 nodes/block, 2x4 acc — round-13 configuration (B-read amortization wins)
template <int K>
__device__ __forceinline__ void gemm_body(int vbg, int t,
    const unsigned short* __restrict__ xf, const unsigned short* __restrict__ Wf,
    const float* __restrict__ a_src, const float* __restrict__ a_dst,
    unsigned short* __restrict__ h, float* __restrict__ s, float* __restrict__ d)
{
    constexpr int NCHUNK = K / 64;
    int lane = t & 63, w = t >> 6;
    int colid = lane & 15, quad = lane >> 4;
    int nb = vbg * 32;

    f32x4 acc[2][4];
#pragma unroll
    for (int mt = 0; mt < 2; mt++)
#pragma unroll
        for (int nt = 0; nt < 4; nt++)
#pragma unroll
            for (int r = 0; r < 4; r++) acc[mt][nt][r] = 0.f;

#pragma unroll
    for (int c = 0; c < NCHUNK; c++) {
        const int kc = c * 64;
        f16x8 ah[2][2], bh[4][2];
#pragma unroll
        for (int half = 0; half < 2; half++) {
#pragma unroll
            for (int mt = 0; mt < 2; mt++) {
                size_t aoff = (size_t)(nb + mt * 16 + colid) * K + kc + half * 32 + quad * 8;
                ah[mt][half] = *(const f16x8*)&xf[aoff];
            }
#pragma unroll
            for (int nt = 0; nt < 4; nt++) {
                size_t boff = (size_t)(w * 64 + nt * 16 + colid) * K + kc + half * 32 + quad * 8;
                bh[nt][half] = *(const f16x8*)&Wf[boff];
            }
        }
        __builtin_amdgcn_sched_barrier(0);
#pragma unroll
        for (int half = 0; half < 2; half++)
#pragma unroll
            for (int mt = 0; mt < 2; mt++)
#pragma unroll
                for (int nt = 0; nt < 4; nt++)
                    acc[mt][nt] = __builtin_amdgcn_mfma_f32_16x16x32_f16(ah[mt][half], bh[nt][half], acc[mt][nt], 0, 0, 0);
    }

    // write h (fp16): C/D layout row=quad*4+r (node), col=colid
#pragma unroll
    for (int mt = 0; mt < 2; mt++) {
#pragma unroll
        for (int r = 0; r < 4; r++) {
            int node = nb + mt * 16 + quad * 4 + r;
#pragma unroll
            for (int nt = 0; nt < 4; nt++)
                h[(size_t)node * HF + w * 64 + nt * 16 + colid] = f2h(acc[mt][nt][r]);
        }
    }

    // attention projections for head w
    float as_r[4], ad_r[4];
#pragma unroll
    for (int nt = 0; nt < 4; nt++) {
        as_r[nt] = a_src[w * 64 + nt * 16 + colid];
        ad_r[nt] = a_dst[w * 64 + nt * 16 + colid];
    }
#pragma unroll
    for (int mt = 0; mt < 2; mt++) {
#pragma unroll
        for (int r = 0; r < 4; r++) {
            float ps = 0.f, pd = 0.f;
#pragma unroll
            for (int nt = 0; nt < 4; nt++) {
                ps += acc[mt][nt][r] * as_r[nt];
                pd += acc[mt][nt][r] * ad_r[nt];
            }
#pragma unroll
            for (int m = 1; m < 16; m <<= 1) {
                ps += __shfl_xor(ps, m, 64);
                pd += __shfl_xor(pd, m, 64);
            }
            if (colid == 0) {
                int node = nb + mt * 16 + quad * 4 + r;
                s[(size_t)node * NHEAD + w] = ps;
                d[(size_t)node * NHEAD + w] = pd;
            }
        }
    }
}

// GAT softmax + aggregate, one wave per node.
// Round-13: chunk-0 h-gathers issued BEFORE the softmax reduction.
__device__ __forceinline__ void aggr_body(int vba, int t,
    const unsigned short* __restrict__ h, const float* __restrict__ s, const float* __restrict__ d,
    const int* __restrict__ offs, const int* __restrict__ csr_src,
    const float* __restrict__ bias, unsigned short* __restrict__ out)
{
    int lane = t & 63;
    int wv = t >> 6;
    int node = vba * 4 + wv;
    int eh = lane >> 5;
    int p = lane & 31;
    int hd2 = p >> 3;
    int f0 = p * 8;
    int lo = offs[node], hi = offs[node + 1];
    int deg = hi - lo;

    float a[8];
#pragma unroll
    for (int j = 0; j < 8; j++) a[j] = 0.f;
    float inv;

    if (deg <= 64) {
        int slot = lane >> 2, hd = lane & 3;
        float dn = d[(size_t)node * NHEAD + hd];
        float ev[4];
        int sv[4];
#pragma unroll
        for (int c = 0; c < 4; c++) {
            int k = c * 16 + slot;
            float e = -3.402823466e38f;
            int src = 0;
            if (k < deg) {
                src = csr_src[lo + k];
                float ee = s[(size_t)src * NHEAD + hd] + dn;
                e = fmaxf(ee, 0.2f * ee);
            }
            ev[c] = e; sv[c] = src;
        }

        // early: shuffle chunk-0 source rows and ISSUE the gathers now
        int sr0[16];
        u16x8 hv0[16];
#pragma unroll
        for (int cc = 0; cc < 2; cc++)
#pragma unroll
            for (int u = 0; u < 8; u++) {
                int sl = (u * 2 + eh) * 4 + hd2;
                sr0[cc * 8 + u] = __shfl(sv[cc], sl);
            }
#pragma unroll
        for (int u = 0; u < 16; u++)
            hv0[u] = *(const u16x8*)(h + (size_t)sr0[u] * HF + f0);

        // softmax while the gathers are in flight
        float mx = fmaxf(fmaxf(ev[0], ev[1]), fmaxf(ev[2], ev[3]));
#pragma unroll
        for (int m = 4; m < 64; m <<= 1) mx = fmaxf(mx, __shfl_xor(mx, m, 64));
        float den = 0.f;
#pragma unroll
        for (int c = 0; c < 4; c++) {
            ev[c] = __expf(ev[c] - mx);  // invalid slots -> 0
            den += ev[c];
        }
#pragma unroll
        for (int m = 4; m < 64; m <<= 1) den += __shfl_xor(den, m, 64);

        inv = 1.f / __shfl(den, hd2);

        // chunk-0 FMA (ex shuffles post-exp; same order as before)
#pragma unroll
        for (int cc = 0; cc < 2; cc++)
#pragma unroll
            for (int u = 0; u < 8; u++) {
                int sl = (u * 2 + eh) * 4 + hd2;
                float ex = __shfl(ev[cc], sl);
                int uu = cc * 8 + u;
#pragma unroll
                for (int j = 0; j < 8; j++) a[j] += ex * h2f(hv0[uu][j]);
            }

        // chunk 1 (edges 32..63) — rare (deg > 32), serial as before
        if (deg > 32) {
            float ex[16]; int sr[16]; u16x8 hv[16];
#pragma unroll
            for (int cc = 0; cc < 2; cc++) {
                int c = 2 + cc;
#pragma unroll
                for (int u = 0; u < 8; u++) {
                    int sl = (u * 2 + eh) * 4 + hd2;
                    ex[cc * 8 + u] = __shfl(ev[c], sl);
                    sr[cc * 8 + u] = __shfl(sv[c], sl);
                }
            }
#pragma unroll
            for (int u = 0; u < 16; u++)
                hv[u] = *(const u16x8*)(h + (size_t)sr[u] * HF + f0);
#pragma unroll
            for (int u = 0; u < 16; u++)
#pragma unroll
                for (int j = 0; j < 8; j++) a[j] += ex[u] * h2f(hv[u][j]);
        }
    } else {
        float dn2 = d[(size_t)node * NHEAD + hd2];
        float mx = -3.402823466e38f;
        for (int i = lo; i < hi; i++) {
            int src = csr_src[i];
            float e = s[(size_t)src * NHEAD + hd2] + dn2;
            e = fmaxf(e, 0.2f * e);
            mx = fmaxf(mx, e);
        }
        float den = 0.f;
        for (int i = lo + eh; i < hi; i += 2) {
            int src = csr_src[i];
            float e = s[(size_t)src * NHEAD + hd2] + dn2;
            e = fmaxf(e, 0.2f * e);
            float ex = __expf(e - mx);
            den += ex;
            u16x8 hv = *(const u16x8*)(h + (size_t)src * HF + f0);
#pragma unroll
            for (int j = 0; j < 8; j++) a[j] += ex * h2f(hv[j]);
        }
        den += __shfl_xor(den, 32, 64);
        inv = 1.f / den;
    }

#pragma unroll
    for (int j = 0; j < 8; j++) a[j] += __shfl_xor(a[j], 32, 64);

    if (eh == 0) {
        u16x8 ov;
#pragma unroll
        for (int j = 0; j < 8; j++)
            ov[j] = f2h(fmaxf(a[j] * inv + bias[f0 + j], 0.f));
        *(u16x8*)(out + (size_t)node * HF + f0) = ov;
    }
}

// per-graph column max via register running-max; ~1 atomic flush / 32 rows
__device__ __forceinline__ void slab_body(int vbs, int t,
    const unsigned short* __restrict__ x, const int* __restrict__ batch,
    int* __restrict__ g, int coloff)
{
    int f = t;
    int r0 = vbs * 32;
    int cur = batch[r0];
    float m = 0.f;
    for (int r = r0; r < r0 + 32; r += 4) {
        float v[4]; int bb[4];
#pragma unroll
        for (int i = 0; i < 4; i++) {
            v[i] = h2f(x[(size_t)(r + i) * HF + f]);
            bb[i] = batch[r + i];
        }
#pragma unroll
        for (int i = 0; i < 4; i++) {
            if (bb[i] != cur) {
                atomicMax(&g[cur * AGGIN + coloff + f], __float_as_int(m));
                m = 0.f; cur = bb[i];
            }
            m = fmaxf(m, v[i]);
        }
    }
    atomicMax(&g[cur * AGGIN + coloff + f], __float_as_int(m));
}

// ---------------- kernels ----------------

// dispatch 1: fw FIRST (longest blocks -> earliest issue), then count/convert/encode
__global__ __launch_bounds__(256) void k_prep_enc(MegaParams P)
{
    __shared__ char smem[96 * 132 * 4];   // 50688 B; fw uses 34816 B of it
    int b = blockIdx.x;
    int fwtot = P.fused ? (FW_BLOCKS + FWB_BLOCKS) : 0;
    if (b < fwtot) {
        if (b < FW_BLOCKS)
            fw_body(b, threadIdx.x, (float*)smem, P.muW, P.vW, P.aggW, P.Wf);
        else
            fwbias_body(b - FW_BLOCKS, threadIdx.x, P.muW, P.mub, P.vW, P.varb,
                        P.aggb, P.bf);
        return;
    }
    b -= fwtot;
    if (b < EDGE_BLOCKS4) {
        count_body(b, threadIdx.x, P.ei, P.cnt);
    } else if (b < EDGE_BLOCKS4 + CONV_BLOCKS) {
        convert_body(b - EDGE_BLOCKS4, threadIdx.x, P.W1, P.W2, P.W3,
                     P.W1f, P.W2f, P.W3f);
    } else {
        float* wlds = (float*)smem;
        float* xlds = wlds + 64 * 132;
        encode_body(b - (EDGE_BLOCKS4 + CONV_BLOCKS), threadIdx.x, wlds, xlds,
                    P.sfeat, P.bfeat, P.smask, P.bmask, P.sW, P.sb, P.bW, P.bb,
                    P.batch, P.x0, P.gi);
    }
}

// CSR scan: 1024 threads — verbatim baseline
__global__ __launch_bounds__(1024) void k_scan(MegaParams P)
{
    const int* deg = P.cnt;
    int* offs = P.offs;
    __shared__ int wt[16];
    const int per = (NNODES + 1023) / 1024; // 20
    int t = threadIdx.x, lane = t & 63, w = t >> 6;
    int start = t * per;
    int end = start + per; if (end > NNODES) end = NNODES;
    int s = 0;
    for (int i = start; i < end; i++) s += deg[i];
    int pref = s;
#pragma unroll
    for (int m = 1; m < 64; m <<= 1) {
        int v = __shfl_up(pref, m, 64);
        if (lane >= m) pref += v;
    }
    if (lane == 63) wt[w] = pref;
    __syncthreads();
    int wadd = 0;
    for (int i = 0; i < w; i++) wadd += wt[i];
    int acc = wadd + pref - s; // exclusive prefix
    for (int i = start; i < end; i++) { offs[i] = acc; acc += deg[i]; }
    if (t == 1023) offs[NNODES] = NEP;
}

// GEMM with extra blocks doing either scatter (slabcol<0) or seg-max slab
template <int K>
__global__ __launch_bounds__(256, 2) void k_gemm(MegaParams P,
    const unsigned short* xf, const unsigned short* Wf,
    const float* a_src, const float* a_dst, int slabcol)
{
    if ((int)blockIdx.x >= GEMM_BLOCKS) {
        if (slabcol >= 0)
            slab_body(blockIdx.x - GEMM_BLOCKS, threadIdx.x, xf, P.batch, P.gi, slabcol);
        else
            scatter_body(blockIdx.x - GEMM_BLOCKS, threadIdx.x, P.ei, P.offs, P.cnt2, P.csr);
        return;
    }
    gemm_body<K>(blockIdx.x, threadIdx.x, xf, Wf, a_src, a_dst, P.h, P.s, P.d);
}

__global__ __launch_bounds__(256) void k_aggr(MegaParams P, const float* bias)
{
    aggr_body(blockIdx.x, threadIdx.x, P.h, P.s, P.d, P.offs, P.csr, bias, P.xA);
}

__global__ __launch_bounds__(256) void k_slab(MegaParams P, int coloff)
{
    slab_body(blockIdx.x, threadIdx.x, P.xA, P.batch, P.gi, coloff);
}

// fused tail: out[half,r,c] = g[r,:] . Wf[half,c,:] + bf[half,c]
__global__ __launch_bounds__(256) void k_head_fused(MegaParams P)
{
    int idx = blockIdx.x * 256 + threadIdx.x; // 2*64*512
    int half = idx >> 15;
    int j = idx & 32767;
    int r = j >> 9, c = j & 511;
    const float4* gv = (const float4*)(P.g + (size_t)r * AGGIN);
    const float4* wv = (const float4*)(P.Wf + ((size_t)(half * 512) + c) * 832);
    float acc = 0.f;
#pragma unroll 4
    for (int k = 0; k < AGGIN / 4; k++) {
        float4 a = gv[k], w = wv[k];
        acc += a.x * w.x + a.y * w.y + a.z * w.z + a.w * w.w;
    }
    P.out[idx] = acc + P.bf[half * 512 + c];
}

// fallback tail (verbatim baseline)
__global__ __launch_bounds__(256) void k_latent(MegaParams P)
{
    int idx = blockIdx.x * 256 + threadIdx.x; // 64*512
    int r = idx >> 9, c = idx & 511;
    const float4* gv = (const float4*)(P.g + (size_t)r * AGGIN);
    const float4* wv = (const float4*)(P.aggW + (size_t)c * AGGIN);
    float acc = 0.f;
#pragma unroll 4
    for (int k = 0; k < AGGIN / 4; k++) {
        float4 a = gv[k], w = wv[k];
        acc += a.x * w.x + a.y * w.y + a.z * w.z + a.w * w.w;
    }
    P.lat[idx] = acc + P.aggb[c];
}

__global__ __launch_bounds__(256) void k_head(MegaParams P)
{
    int idx = blockIdx.x * 256 + threadIdx.x; // 2*64*512
    int half = idx >> 15;
    int j = idx & 32767;
    int r = j >> 9, c = j & 511;
    const float* W = half ? P.vW : P.muW;
    const float* bb = half ? P.varb : P.mub;
    const float4* lv = (const float4*)(P.lat + (size_t)r * LATD);
    const float4* wv = (const float4*)(W + (size_t)c * LATD);
    float acc = 0.f;
#pragma unroll 4
    for (int k = 0; k < LATD / 4; k++) {
        float4 a = lv[k], w = wv[k];
        acc += a.x * w.x + a.y * w.y + a.z * w.z + a.w * w.w;
    }
    P.out[idx] = acc + bb[c];
}

// ---------------- launch ----------------
static inline size_t align16(size_t x) { return (x + 15) & ~(size_t)15; }

extern "C" void kernel_launch(void* const* d_in, const int* in_sizes, int n_in,
                              void* d_out, int out_size, void* d_ws, size_t ws_size,
                              hipStream_t stream)
{
    MegaParams P;
    P.sfeat = (const float*)d_in[0];
    P.bfeat = (const float*)d_in[1];
    P.smask = (const float*)d_in[2];
    P.bmask = (const float*)d_in[3];
    P.ei    = (const int*)d_in[4];
    P.batch = (const int*)d_in[5];
    P.sW = (const float*)d_in[6];
    P.sb = (const float*)d_in[7];
    P.bW = (const float*)d_in[8];
    P.bb = (const float*)d_in[9];
    P.W1 = (const float*)d_in[10];
    P.as1 = (const float*)d_in[11];
    P.ad1 = (const float*)d_in[12];
    P.b1 = (const float*)d_in[13];
    P.W2 = (const float*)d_in[14];
    P.as2 = (const float*)d_in[15];
    P.ad2 = (const float*)d_in[16];
    P.b2 = (const float*)d_in[17];
    P.W3 = (const float*)d_in[18];
    P.as3 = (const float*)d_in[19];
    P.ad3 = (const float*)d_in[20];
    P.b3 = (const float*)d_in[21];
    P.aggW = (const float*)d_in[22];
    P.aggb = (const float*)d_in[23];
    P.muW = (const float*)d_in[24];
    P.mub = (const float*)d_in[25];
    P.vW = (const float*)d_in[26];
    P.varb = (const float*)d_in[27];
    P.out = (float*)d_out;

    char* ws = (char*)d_ws;
    size_t off = 0;
    P.h  = (unsigned short*)(ws + off); off = align16(off + (size_t)NNODES * HF * 2);
    P.x0 = (unsigned short*)(ws + off); off = align16(off + (size_t)MPAD * FDIM * 2);
    P.xA = (unsigned short*)(ws + off); off = align16(off + (size_t)MPAD * HF * 2);
    P.s  = (float*)(ws + off); off = align16(off + (size_t)NNODES * NHEAD * 4);
    P.d  = (float*)(ws + off); off = align16(off + (size_t)NNODES * NHEAD * 4);
    P.offs = (int*)(ws + off); off = align16(off + (size_t)(NNODES + 1) * 4);
    // zero-init region: cnt | cnt2 | g (single memset)
    size_t zstart = off;
    P.cnt  = (int*)(ws + off); off = align16(off + (size_t)NNODES * 4);
    P.cnt2 = (int*)(ws + off); off = align16(off + (size_t)NNODES * 4);
    P.g    = (float*)(ws + off); off = align16(off + (size_t)NGR * AGGIN * 4);
    size_t zbytes = off - zstart;
    P.csr = (int*)(ws + off); off = align16(off + (size_t)NEP * 4);
    P.lat = (float*)(ws + off); off = align16(off + (size_t)NGR * LATD * 4);
    P.W1f = (unsigned short*)(ws + off); off = align16(off + (size_t)HF * FDIM * 2);
    P.W2f = (unsigned short*)(ws + off); off = align16(off + (size_t)HF * HF * 2);
    P.W3f = (unsigned short*)(ws + off); off = align16(off + (size_t)HF * HF * 2);
    // fused tail buffers (optional — runtime ws_size check)
    P.Wf = (float*)(ws + off); off = align16(off + (size_t)2 * 512 * 832 * 4);
    P.bf = (float*)(ws + off); off = align16(off + (size_t)2 * 512 * 4);
    P.fused = (off <= ws_size) ? 1 : 0;

    P.gi = (int*)P.g;

    hipMemsetAsync(ws + zstart, 0, zbytes, stream);

    // 10 dispatches (fused) / 11 (fallback)
    int prep_blocks = EDGE_BLOCKS4 + CONV_BLOCKS + ENC_BLOCKS
                    + (P.fused ? (FW_BLOCKS + FWB_BLOCKS) : 0);
    k_prep_enc<<<prep_blocks, 256, 0, stream>>>(P);
    k_scan<<<1, 1024, 0, stream>>>(P);

    // gemm1 + scatter ride together (mutually independent; both complete before aggr1)
    k_gemm<FDIM><<<GEMM_BLOCKS + EDGE_BLOCKS4, 256, 0, stream>>>(P, P.x0, P.W1f, P.as1, P.ad1, -1);
    k_aggr<<<AGGR_BLOCKS, 256, 0, stream>>>(P, P.b1);

    k_gemm<HF><<<GEMM_BLOCKS + SLAB_BLOCKS, 256, 0, stream>>>(P, P.xA, P.W2f, P.as2, P.ad2, FDIM);
    k_aggr<<<AGGR_BLOCKS, 256, 0, stream>>>(P, P.b2);

    k_gemm<HF><<<GEMM_BLOCKS + SLAB_BLOCKS, 256, 0, stream>>>(P, P.xA, P.W3f, P.as3, P.ad3, FDIM + HF);
    k_aggr<<<AGGR_BLOCKS, 256, 0, stream>>>(P, P.b3);

    k_slab<<<SLAB_BLOCKS, 256, 0, stream>>>(P, FDIM + 2 * HF);

    if (P.fused) {
        k_head_fused<<<(2 * NGR * LATD) / 256, 256, 0, stream>>>(P);
    } else {
        k_latent<<<(NGR * LATD) / 256, 256, 0, stream>>>(P);
        k_head<<<(2 * NGR * LATD) / 256, 256, 0, stream>>>(P);
    }
}